// Round 19
// baseline (107.529 us; speedup 1.0000x reference)
//
#include <hip/hip_runtime.h>
#include <math.h>

#define BB 8
#define LL 1024
#define HH 8
#define DD 64
#define SS 35
#define UU 35
#define BH (BB*HH)
#define NCHK 4           // attention K/V chunks
#define CHK 256          // keys per chunk
#define RPAD 48          // padded row count (35 -> 48, 3 m-tiles)

#define CSBLOCKS BH      // 64 cumsum blocks (first in grid)
#define MBLOCKS (BB*LL)  // 8192 M blocks

typedef __attribute__((ext_vector_type(8))) short short8;
typedef __attribute__((ext_vector_type(4))) float f32x4;

__device__ __forceinline__ size_t qkv_off(int b, int l, int h, int d) {
    return (((size_t)b*LL + l)*HH + h)*DD + d;
}

__device__ __forceinline__ unsigned short f2bf(float x) {
    unsigned int u = __float_as_uint(x);
    u = (u + 0x7fffu + ((u >> 16) & 1u)) >> 16;
    return (unsigned short)u;
}

__device__ __forceinline__ short8 ld_bf8_g(const float* __restrict__ p) {
    float4 x = *reinterpret_cast<const float4*>(p);
    float4 y = *reinterpret_cast<const float4*>(p + 4);
    short8 r;
    r[0] = (short)f2bf(x.x); r[1] = (short)f2bf(x.y);
    r[2] = (short)f2bf(x.z); r[3] = (short)f2bf(x.w);
    r[4] = (short)f2bf(y.x); r[5] = (short)f2bf(y.y);
    r[6] = (short)f2bf(y.z); r[7] = (short)f2bf(y.w);
    return r;
}

// VALU-only 8-lane-group sum via DPP row_shr:N; lane (lane&7)==7 holds group sum. (Proven R10-R18.)
__device__ __forceinline__ float red8_shr(float p) {
    int t;
    t = __builtin_amdgcn_update_dpp(0, __float_as_int(p), 0x111, 0xF, 0xF, true); // row_shr:1
    p += __int_as_float(t);
    t = __builtin_amdgcn_update_dpp(0, __float_as_int(p), 0x112, 0xF, 0xF, true); // row_shr:2
    p += __int_as_float(t);
    t = __builtin_amdgcn_update_dpp(0, __float_as_int(p), 0x114, 0xF, 0xF, true); // row_shr:4
    p += __int_as_float(t);
    return p;
}

// wave-wide fmax / imin: butterfly DPP (all lanes receive the result). (Proven R14-R18.)
__device__ __forceinline__ float wave_fmax64(float x) {
    int t;
    t = __builtin_amdgcn_update_dpp(0, __float_as_int(x), 0xB1, 0xF, 0xF, true);
    x = fmaxf(x, __int_as_float(t));
    t = __builtin_amdgcn_update_dpp(0, __float_as_int(x), 0x4E, 0xF, 0xF, true);
    x = fmaxf(x, __int_as_float(t));
    t = __builtin_amdgcn_update_dpp(0, __float_as_int(x), 0x141, 0xF, 0xF, true);
    x = fmaxf(x, __int_as_float(t));
    t = __builtin_amdgcn_update_dpp(0, __float_as_int(x), 0x140, 0xF, 0xF, true);
    x = fmaxf(x, __int_as_float(t));
    x = fmaxf(x, __shfl_xor(x, 16));
    x = fmaxf(x, __shfl_xor(x, 32));
    return x;
}

__device__ __forceinline__ int wave_imin64(int x) {
    int t;
    t = __builtin_amdgcn_update_dpp(0, x, 0xB1, 0xF, 0xF, true);  x = (t < x) ? t : x;
    t = __builtin_amdgcn_update_dpp(0, x, 0x4E, 0xF, 0xF, true);  x = (t < x) ? t : x;
    t = __builtin_amdgcn_update_dpp(0, x, 0x141, 0xF, 0xF, true); x = (t < x) ? t : x;
    t = __builtin_amdgcn_update_dpp(0, x, 0x140, 0xF, 0xF, true); x = (t < x) ? t : x;
    int y;
    y = __shfl_xor(x, 16); x = (y < x) ? y : x;
    y = __shfl_xor(x, 32); x = (y < x) ? y : x;
    return x;
}

// ---------------- K1: cumsum (blocks 0..63) + M-gather (no duplicate-sample traffic) ----------------
__global__ __launch_bounds__(512, 2) void kernel_M_cumsum(const float* __restrict__ Q,
                                                          const float* __restrict__ K,
                                                          const float* __restrict__ V,
                                                          const int*   __restrict__ sidx,
                                                          float* __restrict__ M,
                                                          float* __restrict__ out) {
    int blk = blockIdx.x;
    if (blk < CSBLOCKS) {
        // ---- full cumsum for one (b,h): 8 segs x 128 rows, two-pass scan ----
        __shared__ float partial[8][64];
        int bh = blk;
        int b = bh >> 3, h = bh & 7;
        int d = threadIdx.x & 63, seg = threadIdx.x >> 6;
        int l0 = seg * 128;
        const float* vp = V + qkv_off(b, l0, h, d);

        float s = 0.f;
#pragma unroll 8
        for (int i = 0; i < 128; i++) s += vp[(size_t)i * (HH * DD)];
        partial[seg][d] = s;
        __syncthreads();
        float run = 0.f;
#pragma unroll
        for (int ss = 0; ss < 7; ss++) {
            float v = partial[ss][d];
            run += (ss < seg) ? v : 0.f;
        }
        float* op = out + qkv_off(b, l0, h, d);
#pragma unroll 8
        for (int i = 0; i < 128; i++) {
            run += vp[(size_t)i * (HH * DD)];
            op[(size_t)i * (HH * DD)] = run / (float)(l0 + i + 1);
        }
    } else {
        // ---- M: one block per (b,q); wave w owns samples {w, w+8, w+16, w+24} (+w+32 if w<3) ----
        __shared__ float s_mx[8][8];
        __shared__ float s_sm[8][8];
        int mblk = blk - CSBLOCKS;       // CSBLOCKS%8==0 keeps XCD pinning
        int b = mblk & 7;                // pins this b's K-slice to one XCD's L2
        int q = mblk >> 3;
        int tid = threadIdx.x;
        int w = tid >> 6, lane = tid & 63;
        int h = lane >> 3, j = lane & 7, dsub = j * 4;

        const float* qb = Q + ((size_t)(b * LL + q) * HH + h) * DD + dsub;
        f32x4 q0 = *reinterpret_cast<const f32x4*>(qb);
        f32x4 q1 = *reinterpret_cast<const f32x4*>(qb + 32);

        const int* sq = sidx + q * SS;
        int sl0 = sq[w], sl1 = sq[w + 8], sl2 = sq[w + 16], sl3 = sq[w + 24];

        const float* kbase = K + (size_t)b * (LL * HH * DD) + h * DD + dsub;
        const float* kp0 = kbase + (size_t)sl0 * (HH * DD);
        const float* kp1 = kbase + (size_t)sl1 * (HH * DD);
        const float* kp2 = kbase + (size_t)sl2 * (HH * DD);
        const float* kp3 = kbase + (size_t)sl3 * (HH * DD);

        f32x4 a0, a1, a2, a3, c0, c1, c2, c3, a4, c4;
        asm volatile("global_load_dwordx4 %0, %1, off"            : "=v"(a0) : "v"(kp0));
        asm volatile("global_load_dwordx4 %0, %1, off offset:128" : "=v"(c0) : "v"(kp0));
        asm volatile("global_load_dwordx4 %0, %1, off"            : "=v"(a1) : "v"(kp1));
        asm volatile("global_load_dwordx4 %0, %1, off offset:128" : "=v"(c1) : "v"(kp1));
        asm volatile("global_load_dwordx4 %0, %1, off"            : "=v"(a2) : "v"(kp2));
        asm volatile("global_load_dwordx4 %0, %1, off offset:128" : "=v"(c2) : "v"(kp2));
        asm volatile("global_load_dwordx4 %0, %1, off"            : "=v"(a3) : "v"(kp3));
        asm volatile("global_load_dwordx4 %0, %1, off offset:128" : "=v"(c3) : "v"(kp3));
        bool have5 = (w < 3);            // wave-uniform branch: no dup-row traffic for w>=3
        if (have5) {
            const float* kp4 = kbase + (size_t)sq[w + 32] * (HH * DD);
            asm volatile("global_load_dwordx4 %0, %1, off"            : "=v"(a4) : "v"(kp4));
            asm volatile("global_load_dwordx4 %0, %1, off offset:128" : "=v"(c4) : "v"(kp4));
        }
        asm volatile("s_waitcnt vmcnt(0)" ::: "memory");
        __builtin_amdgcn_sched_barrier(0);   // rule #18: keep consumers after the waitcnt

        float mx = -INFINITY, sm = 0.f;
        {
            float d0 = q0.x * a0.x + q0.y * a0.y + q0.z * a0.z + q0.w * a0.w
                     + q1.x * c0.x + q1.y * c0.y + q1.z * c0.z + q1.w * c0.w;
            d0 = red8_shr(d0);
            mx = fmaxf(mx, d0); sm += d0;
            float d1 = q0.x * a1.x + q0.y * a1.y + q0.z * a1.z + q0.w * a1.w
                     + q1.x * c1.x + q1.y * c1.y + q1.z * c1.z + q1.w * c1.w;
            d1 = red8_shr(d1);
            mx = fmaxf(mx, d1); sm += d1;
            float d2 = q0.x * a2.x + q0.y * a2.y + q0.z * a2.z + q0.w * a2.w
                     + q1.x * c2.x + q1.y * c2.y + q1.z * c2.z + q1.w * c2.w;
            d2 = red8_shr(d2);
            mx = fmaxf(mx, d2); sm += d2;
            float d3 = q0.x * a3.x + q0.y * a3.y + q0.z * a3.z + q0.w * a3.w
                     + q1.x * c3.x + q1.y * c3.y + q1.z * c3.z + q1.w * c3.w;
            d3 = red8_shr(d3);
            mx = fmaxf(mx, d3); sm += d3;
            if (have5) {
                float d4 = q0.x * a4.x + q0.y * a4.y + q0.z * a4.z + q0.w * a4.w
                         + q1.x * c4.x + q1.y * c4.y + q1.z * c4.z + q1.w * c4.w;
                d4 = red8_shr(d4);
                mx = fmaxf(mx, d4); sm += d4;
            }
        }

        if (j == 7) { s_mx[w][h] = mx; s_sm[w][h] = sm; }
        __syncthreads();
        if (tid < 8) {
            float m2 = -INFINITY, s2 = 0.f;
#pragma unroll
            for (int ww = 0; ww < 8; ww++) {
                m2 = fmaxf(m2, s_mx[ww][tid]);
                s2 += s_sm[ww][tid];
            }
            M[(b * HH + tid) * LL + q] = m2 - s2 * (1.0f / LL);
        }
    }
}

// ---------------- K2: attn_part + fused topk + last-block COMBINE ----------------
__global__ __launch_bounds__(256) void kernel_attn_part(const float* __restrict__ Q,
                                                        const float* __restrict__ K,
                                                        const float* __restrict__ V,
                                                        const float* __restrict__ M,
                                                        float* __restrict__ m_ws,
                                                        float* __restrict__ se_ws,
                                                        float* __restrict__ pv_ws,
                                                        int*   __restrict__ cnt,
                                                        float* __restrict__ out) {
    __shared__ unsigned short vt[64 * CHK];      // V^T, 16B-slot swizzled
    __shared__ unsigned short p_lds[RPAD * CHK]; // P (exp'd scores), bf16
    __shared__ float red_m[4][RPAD];
    __shared__ float red_se[4][RPAD];
    __shared__ int   qpos_s[RPAD];
    __shared__ int   s_done;

    const int blk = blockIdx.x;          // bh*NCHK + ch
    const int bh  = blk >> 2;
    const int ch  = blk & 3;
    const int b   = bh >> 3, h = bh & 7;
    const int l0  = ch * CHK;
    const int tid = threadIdx.x;
    const int w    = tid >> 6;
    const int lane = tid & 63;
    const int c    = lane & 15;
    const int g    = lane >> 4;
    const float scale = 0.125f;

    if (w == 0) {
        // ---- wave 0: top-35 from M (DPP argmax), redundant across the bh's 4 blocks ----
        float v[16];
#pragma unroll
        for (int i = 0; i < 16; i++) v[i] = M[bh * LL + i * 64 + lane];
        int last = 0;
        for (int k = 0; k < UU; k++) {
            float bv = -INFINITY; int bslot = 0;
#pragma unroll
            for (int i = 0; i < 16; i++) {
                if (v[i] > bv) { bv = v[i]; bslot = i; }  // ascending i -> lowest idx on tie
            }
            float wm = wave_fmax64(bv);
            int gidx = (bv == wm) ? (bslot * 64 + lane) : 0x7fffffff;
            int widx = wave_imin64(gidx);                  // all lanes hold result
            if (lane == 0) qpos_s[k] = widx;
            if (k == UU - 1) last = widx;
            if ((widx & 63) == lane) {
                int slot = widx >> 6;
#pragma unroll
                for (int i = 0; i < 16; i++) if (i == slot) v[i] = -INFINITY;
            }
        }
        if (lane >= UU && lane < RPAD) qpos_s[lane] = last;
    } else {
        // ---- waves 1-3: stage V^T chunk (2048 tasks over 192 threads) ----
        int t3 = tid - 64;
#pragma unroll
        for (int i = 0; i < 11; i++) {
            int task = i * 192 + t3;
            if (task < 2048) {
                int d   = task & 63;
                int lq8 = task >> 6;
                float vv[8];
#pragma unroll
                for (int jj = 0; jj < 8; jj++)
                    vv[jj] = V[qkv_off(b, l0 + lq8 * 8 + jj, h, d)];
                short8 pk;
#pragma unroll
                for (int jj = 0; jj < 8; jj++) pk[jj] = (short)f2bf(vv[jj]);
                *reinterpret_cast<short8*>(vt + d * CHK + (((lq8 ^ (d & 31)) << 3))) = pk;
            }
        }
    }
    __syncthreads();

    f32x4 acc[3][4];
#pragma unroll
    for (int mt = 0; mt < 3; mt++)
#pragma unroll
        for (int nt = 0; nt < 4; nt++) acc[mt][nt] = (f32x4){0.f, 0.f, 0.f, 0.f};

#pragma unroll
    for (int ks = 0; ks < 2; ks++) {
        int k0 = ks * 32 + g * 8;
        short8 af[3];
#pragma unroll
        for (int mt = 0; mt < 3; mt++) {
            int row = mt * 16 + c;
            af[mt] = ld_bf8_g(Q + qkv_off(b, qpos_s[row], h, k0));
        }
#pragma unroll
        for (int nt = 0; nt < 4; nt++) {
            int kl = l0 + w * 64 + nt * 16 + c;
            short8 bf = ld_bf8_g(K + qkv_off(b, kl, h, k0));
#pragma unroll
            for (int mt = 0; mt < 3; mt++)
                acc[mt][nt] = __builtin_amdgcn_mfma_f32_16x16x32_bf16(af[mt], bf, acc[mt][nt], 0, 0, 0);
        }
    }

    float tmax[3][4];
#pragma unroll
    for (int mt = 0; mt < 3; mt++)
#pragma unroll
        for (int r = 0; r < 4; r++) {
            float m = fmaxf(fmaxf(acc[mt][0][r], acc[mt][1][r]),
                            fmaxf(acc[mt][2][r], acc[mt][3][r]));
            m = fmaxf(m, __shfl_xor(m, 1));
            m = fmaxf(m, __shfl_xor(m, 2));
            m = fmaxf(m, __shfl_xor(m, 4));
            m = fmaxf(m, __shfl_xor(m, 8));
            tmax[mt][r] = m;
        }
    if (c == 0) {
#pragma unroll
        for (int mt = 0; mt < 3; mt++)
#pragma unroll
            for (int r = 0; r < 4; r++)
                red_m[w][mt * 16 + g * 4 + r] = tmax[mt][r];
    }
    __syncthreads();

    float tse[3][4];
#pragma unroll
    for (int mt = 0; mt < 3; mt++)
#pragma unroll
        for (int r = 0; r < 4; r++) {
            int row = mt * 16 + g * 4 + r;
            float m = fmaxf(fmaxf(red_m[0][row], red_m[1][row]),
                            fmaxf(red_m[2][row], red_m[3][row]));
            float s = 0.f;
#pragma unroll
            for (int nt = 0; nt < 4; nt++) {
                float p = __expf(scale * (acc[mt][nt][r] - m));
                acc[mt][nt][r] = p;
                s += p;
                p_lds[row * CHK + w * 64 + nt * 16 + c] = f2bf(p);
            }
            s += __shfl_xor(s, 1);
            s += __shfl_xor(s, 2);
            s += __shfl_xor(s, 4);
            s += __shfl_xor(s, 8);
            tse[mt][r] = s;
        }
    if (c == 0) {
#pragma unroll
        for (int mt = 0; mt < 3; mt++)
#pragma unroll
            for (int r = 0; r < 4; r++)
                red_se[w][mt * 16 + g * 4 + r] = tse[mt][r];
    }
    __syncthreads();

    if (tid < RPAD) {
        float mm = fmaxf(fmaxf(red_m[0][tid], red_m[1][tid]),
                         fmaxf(red_m[2][tid], red_m[3][tid]));
        float ss = red_se[0][tid] + red_se[1][tid] + red_se[2][tid] + red_se[3][tid];
        m_ws[blk * RPAD + tid]  = mm;
        se_ws[blk * RPAD + tid] = ss;
    }

    f32x4 acc2[3];
#pragma unroll
    for (int mt = 0; mt < 3; mt++) acc2[mt] = (f32x4){0.f, 0.f, 0.f, 0.f};

#pragma unroll
    for (int ks = 0; ks < 8; ks++) {
        int slot = ks * 4 + g;
        int d    = w * 16 + c;
        short8 bf = *reinterpret_cast<const short8*>(
            vt + d * CHK + ((slot ^ (d & 31)) << 3));
#pragma unroll
        for (int mt = 0; mt < 3; mt++) {
            short8 af = *reinterpret_cast<const short8*>(
                p_lds + (mt * 16 + c) * CHK + ks * 32 + g * 8);
            acc2[mt] = __builtin_amdgcn_mfma_f32_16x16x32_bf16(af, bf, acc2[mt], 0, 0, 0);
        }
    }

#pragma unroll
    for (int mt = 0; mt < 3; mt++)
#pragma unroll
        for (int r = 0; r < 4; r++) {
            int row = mt * 16 + g * 4 + r;
            pv_ws[((size_t)blk * RPAD + row) * 64 + w * 16 + c] = acc2[mt][r];
        }

    // ---- last-block-done combine (replaces kernel_attn_comb) ----
    __threadfence();                       // release: partials visible device-wide
    __syncthreads();                       // all threads' writes fenced before the atomic
    if (tid == 0) {
        int old = atomicAdd(&cnt[bh], 1);
        s_done = (old == NCHK - 1);
    }
    __syncthreads();
    if (s_done) {
        __threadfence();                   // acquire: see other XCDs' partials
        for (int idx = tid; idx < UU * 64; idx += 256) {
            int r = idx >> 6, d = idx & 63;
            float mc[NCHK];
            float mm = -INFINITY;
#pragma unroll
            for (int c2 = 0; c2 < NCHK; c2++) {
                mc[c2] = m_ws[(bh * NCHK + c2) * RPAD + r];
                mm = fmaxf(mm, mc[c2]);
            }
            float num = 0.f, den = 0.f;
#pragma unroll
            for (int c2 = 0; c2 < NCHK; c2++) {
                float f = __expf(scale * (mc[c2] - mm));
                num += f * pv_ws[((size_t)(bh * NCHK + c2) * RPAD + r) * 64 + d];
                den += f * se_ws[(bh * NCHK + c2) * RPAD + r];
            }
            out[qkv_off(b, qpos_s[r], h, d)] = num / den;
        }
    }
}

extern "C" void kernel_launch(void* const* d_in, const int* in_sizes, int n_in,
                              void* d_out, int out_size, void* d_ws, size_t ws_size,
                              hipStream_t stream) {
    const float* Q    = (const float*)d_in[0];
    const float* K    = (const float*)d_in[1];
    const float* V    = (const float*)d_in[2];
    const int*   sidx = (const int*)d_in[3];
    float* out = (float*)d_out;

    char* ws = (char*)d_ws;
    float* M     = (float*)(ws);                // 256 KiB
    int*   cnt   = (int*)  (ws + 262144);       // 256 B (per-bh arrival counters)
    float* m_ws  = (float*)(ws + 272384);       // 48 KiB
    float* se_ws = (float*)(ws + 321536);       // 48 KiB
    float* pv_ws = (float*)(ws + 370688);       // 3 MiB

    hipMemsetAsync(cnt, 0, BH * sizeof(int), stream);
    kernel_M_cumsum <<<CSBLOCKS + MBLOCKS, 512, 0, stream>>>(Q, K, V, sidx, M, out);
    kernel_attn_part<<<BH * NCHK, 256, 0, stream>>>(Q, K, V, M, m_ws, se_ws, pv_ws, cnt, out);
}

// Round 20
// 66.081 us; speedup vs baseline: 1.6272x; 1.6272x over previous
//
#include <hip/hip_runtime.h>
#include <math.h>

#define BB 8
#define LL 1024
#define HH 8
#define DD 64
#define SS 35
#define UU 35
#define BH (BB*HH)
#define NCHK 4           // attention K/V chunks
#define CHK 256          // keys per chunk
#define RPAD 48          // padded row count (35 -> 48, 3 m-tiles)

#define CSBLOCKS BH      // 64 cumsum blocks (first in grid)
#define MBLOCKS (BB*LL)  // 8192 M blocks

typedef __attribute__((ext_vector_type(8))) short short8;
typedef __attribute__((ext_vector_type(4))) float f32x4;

__device__ __forceinline__ size_t qkv_off(int b, int l, int h, int d) {
    return (((size_t)b*LL + l)*HH + h)*DD + d;
}

__device__ __forceinline__ unsigned short f2bf(float x) {
    unsigned int u = __float_as_uint(x);
    u = (u + 0x7fffu + ((u >> 16) & 1u)) >> 16;
    return (unsigned short)u;
}

__device__ __forceinline__ short8 ld_bf8_g(const float* __restrict__ p) {
    float4 x = *reinterpret_cast<const float4*>(p);
    float4 y = *reinterpret_cast<const float4*>(p + 4);
    short8 r;
    r[0] = (short)f2bf(x.x); r[1] = (short)f2bf(x.y);
    r[2] = (short)f2bf(x.z); r[3] = (short)f2bf(x.w);
    r[4] = (short)f2bf(y.x); r[5] = (short)f2bf(y.y);
    r[6] = (short)f2bf(y.z); r[7] = (short)f2bf(y.w);
    return r;
}

// VALU-only 8-lane-group sum via DPP row_shr:N; lane (lane&7)==7 holds group sum. (Proven R10-R18.)
__device__ __forceinline__ float red8_shr(float p) {
    int t;
    t = __builtin_amdgcn_update_dpp(0, __float_as_int(p), 0x111, 0xF, 0xF, true); // row_shr:1
    p += __int_as_float(t);
    t = __builtin_amdgcn_update_dpp(0, __float_as_int(p), 0x112, 0xF, 0xF, true); // row_shr:2
    p += __int_as_float(t);
    t = __builtin_amdgcn_update_dpp(0, __float_as_int(p), 0x114, 0xF, 0xF, true); // row_shr:4
    p += __int_as_float(t);
    return p;
}

// wave-wide fmax / imin: butterfly DPP (all lanes receive the result). (Proven R14-R18.)
__device__ __forceinline__ float wave_fmax64(float x) {
    int t;
    t = __builtin_amdgcn_update_dpp(0, __float_as_int(x), 0xB1, 0xF, 0xF, true);
    x = fmaxf(x, __int_as_float(t));
    t = __builtin_amdgcn_update_dpp(0, __float_as_int(x), 0x4E, 0xF, 0xF, true);
    x = fmaxf(x, __int_as_float(t));
    t = __builtin_amdgcn_update_dpp(0, __float_as_int(x), 0x141, 0xF, 0xF, true);
    x = fmaxf(x, __int_as_float(t));
    t = __builtin_amdgcn_update_dpp(0, __float_as_int(x), 0x140, 0xF, 0xF, true);
    x = fmaxf(x, __int_as_float(t));
    x = fmaxf(x, __shfl_xor(x, 16));
    x = fmaxf(x, __shfl_xor(x, 32));
    return x;
}

__device__ __forceinline__ int wave_imin64(int x) {
    int t;
    t = __builtin_amdgcn_update_dpp(0, x, 0xB1, 0xF, 0xF, true);  x = (t < x) ? t : x;
    t = __builtin_amdgcn_update_dpp(0, x, 0x4E, 0xF, 0xF, true);  x = (t < x) ? t : x;
    t = __builtin_amdgcn_update_dpp(0, x, 0x141, 0xF, 0xF, true); x = (t < x) ? t : x;
    t = __builtin_amdgcn_update_dpp(0, x, 0x140, 0xF, 0xF, true); x = (t < x) ? t : x;
    int y;
    y = __shfl_xor(x, 16); x = (y < x) ? y : x;
    y = __shfl_xor(x, 32); x = (y < x) ? y : x;
    return x;
}

// ---------------- K1: cumsum (blocks 0..63) + M-gather (asm loads, trimmed traffic) ----------------
__global__ __launch_bounds__(512, 2) void kernel_M_cumsum(const float* __restrict__ Q,
                                                          const float* __restrict__ K,
                                                          const float* __restrict__ V,
                                                          const int*   __restrict__ sidx,
                                                          float* __restrict__ M,
                                                          float* __restrict__ out) {
    int blk = blockIdx.x;
    if (blk < CSBLOCKS) {
        // ---- full cumsum for one (b,h): 8 segs x 128 rows, two-pass scan ----
        __shared__ float partial[8][64];
        int bh = blk;
        int b = bh >> 3, h = bh & 7;
        int d = threadIdx.x & 63, seg = threadIdx.x >> 6;
        int l0 = seg * 128;
        const float* vp = V + qkv_off(b, l0, h, d);

        float s = 0.f;
#pragma unroll 8
        for (int i = 0; i < 128; i++) s += vp[(size_t)i * (HH * DD)];
        partial[seg][d] = s;
        __syncthreads();
        float run = 0.f;
#pragma unroll
        for (int ss = 0; ss < 7; ss++) {
            float v = partial[ss][d];
            run += (ss < seg) ? v : 0.f;
        }
        float* op = out + qkv_off(b, l0, h, d);
#pragma unroll 8
        for (int i = 0; i < 128; i++) {
            run += vp[(size_t)i * (HH * DD)];
            op[(size_t)i * (HH * DD)] = run / (float)(l0 + i + 1);
        }
    } else {
        // ---- M: one block per (b,q); wave w owns samples {w, w+8, w+16, w+24} (+w+32 if w<3) ----
        __shared__ float s_mx[8][8];
        __shared__ float s_sm[8][8];
        int mblk = blk - CSBLOCKS;       // CSBLOCKS%8==0 keeps XCD pinning
        int b = mblk & 7;                // pins this b's K-slice to one XCD's L2
        int q = mblk >> 3;
        int tid = threadIdx.x;
        int w = tid >> 6, lane = tid & 63;
        int h = lane >> 3, j = lane & 7, dsub = j * 4;

        const float* qb = Q + ((size_t)(b * LL + q) * HH + h) * DD + dsub;
        f32x4 q0 = *reinterpret_cast<const f32x4*>(qb);
        f32x4 q1 = *reinterpret_cast<const f32x4*>(qb + 32);

        const int* sq = sidx + q * SS;
        int sl0 = sq[w], sl1 = sq[w + 8], sl2 = sq[w + 16], sl3 = sq[w + 24];

        const float* kbase = K + (size_t)b * (LL * HH * DD) + h * DD + dsub;
        const float* kp0 = kbase + (size_t)sl0 * (HH * DD);
        const float* kp1 = kbase + (size_t)sl1 * (HH * DD);
        const float* kp2 = kbase + (size_t)sl2 * (HH * DD);
        const float* kp3 = kbase + (size_t)sl3 * (HH * DD);

        f32x4 a0, a1, a2, a3, c0, c1, c2, c3, a4, c4;
        asm volatile("global_load_dwordx4 %0, %1, off"            : "=v"(a0) : "v"(kp0));
        asm volatile("global_load_dwordx4 %0, %1, off offset:128" : "=v"(c0) : "v"(kp0));
        asm volatile("global_load_dwordx4 %0, %1, off"            : "=v"(a1) : "v"(kp1));
        asm volatile("global_load_dwordx4 %0, %1, off offset:128" : "=v"(c1) : "v"(kp1));
        asm volatile("global_load_dwordx4 %0, %1, off"            : "=v"(a2) : "v"(kp2));
        asm volatile("global_load_dwordx4 %0, %1, off offset:128" : "=v"(c2) : "v"(kp2));
        asm volatile("global_load_dwordx4 %0, %1, off"            : "=v"(a3) : "v"(kp3));
        asm volatile("global_load_dwordx4 %0, %1, off offset:128" : "=v"(c3) : "v"(kp3));
        bool have5 = (w < 3);            // wave-uniform: no dup-row traffic for w>=3
        if (have5) {
            const float* kp4 = kbase + (size_t)sq[w + 32] * (HH * DD);
            asm volatile("global_load_dwordx4 %0, %1, off"            : "=v"(a4) : "v"(kp4));
            asm volatile("global_load_dwordx4 %0, %1, off offset:128" : "=v"(c4) : "v"(kp4));
        }
        asm volatile("s_waitcnt vmcnt(0)" ::: "memory");
        __builtin_amdgcn_sched_barrier(0);   // rule #18: keep consumers after the waitcnt

        float mx = -INFINITY, sm = 0.f;
        {
            float d0 = q0.x * a0.x + q0.y * a0.y + q0.z * a0.z + q0.w * a0.w
                     + q1.x * c0.x + q1.y * c0.y + q1.z * c0.z + q1.w * c0.w;
            d0 = red8_shr(d0);
            mx = fmaxf(mx, d0); sm += d0;
            float d1 = q0.x * a1.x + q0.y * a1.y + q0.z * a1.z + q0.w * a1.w
                     + q1.x * c1.x + q1.y * c1.y + q1.z * c1.z + q1.w * c1.w;
            d1 = red8_shr(d1);
            mx = fmaxf(mx, d1); sm += d1;
            float d2 = q0.x * a2.x + q0.y * a2.y + q0.z * a2.z + q0.w * a2.w
                     + q1.x * c2.x + q1.y * c2.y + q1.z * c2.z + q1.w * c2.w;
            d2 = red8_shr(d2);
            mx = fmaxf(mx, d2); sm += d2;
            float d3 = q0.x * a3.x + q0.y * a3.y + q0.z * a3.z + q0.w * a3.w
                     + q1.x * c3.x + q1.y * c3.y + q1.z * c3.z + q1.w * c3.w;
            d3 = red8_shr(d3);
            mx = fmaxf(mx, d3); sm += d3;
            if (have5) {
                float d4 = q0.x * a4.x + q0.y * a4.y + q0.z * a4.z + q0.w * a4.w
                         + q1.x * c4.x + q1.y * c4.y + q1.z * c4.z + q1.w * c4.w;
                d4 = red8_shr(d4);
                mx = fmaxf(mx, d4); sm += d4;
            }
        }

        if (j == 7) { s_mx[w][h] = mx; s_sm[w][h] = sm; }
        __syncthreads();
        if (tid < 8) {
            float m2 = -INFINITY, s2 = 0.f;
#pragma unroll
            for (int ww = 0; ww < 8; ww++) {
                m2 = fmaxf(m2, s_mx[ww][tid]);
                s2 += s_sm[ww][tid];
            }
            M[(b * HH + tid) * LL + q] = m2 - s2 * (1.0f / LL);
        }
    }
}

// ---------------- K2: attn_part with FUSED topk (wave 0) ∥ V-staging (waves 1-3) ----------------
__global__ __launch_bounds__(256) void kernel_attn_part(const float* __restrict__ Q,
                                                        const float* __restrict__ K,
                                                        const float* __restrict__ V,
                                                        const float* __restrict__ M,
                                                        int*   __restrict__ top,
                                                        float* __restrict__ m_ws,
                                                        float* __restrict__ se_ws,
                                                        float* __restrict__ pv_ws) {
    __shared__ unsigned short vt[64 * CHK];      // V^T, 16B-slot swizzled
    __shared__ unsigned short p_lds[RPAD * CHK]; // P (exp'd scores), bf16
    __shared__ float red_m[4][RPAD];
    __shared__ float red_se[4][RPAD];
    __shared__ int   qpos_s[RPAD];

    const int blk = blockIdx.x;          // bh*NCHK + ch
    const int bh  = blk >> 2;
    const int ch  = blk & 3;
    const int b   = bh >> 3, h = bh & 7;
    const int l0  = ch * CHK;
    const int tid = threadIdx.x;
    const int w    = tid >> 6;
    const int lane = tid & 63;
    const int c    = lane & 15;
    const int g    = lane >> 4;
    const float scale = 0.125f;

    if (w == 0) {
        // ---- wave 0: top-35 from M (DPP argmax), redundant across the bh's 4 blocks ----
        float v[16];
#pragma unroll
        for (int i = 0; i < 16; i++) v[i] = M[bh * LL + i * 64 + lane];
        int last = 0;
        for (int k = 0; k < UU; k++) {
            float bv = -INFINITY; int bslot = 0;
#pragma unroll
            for (int i = 0; i < 16; i++) {
                if (v[i] > bv) { bv = v[i]; bslot = i; }  // ascending i -> lowest idx on tie
            }
            float wm = wave_fmax64(bv);
            int gidx = (bv == wm) ? (bslot * 64 + lane) : 0x7fffffff;
            int widx = wave_imin64(gidx);                  // all lanes hold result
            if (lane == 0) qpos_s[k] = widx;
            if (k == UU - 1) last = widx;
            if ((widx & 63) == lane) {
                int slot = widx >> 6;
#pragma unroll
                for (int i = 0; i < 16; i++) if (i == slot) v[i] = -INFINITY;
            }
        }
        if (lane >= UU && lane < RPAD) qpos_s[lane] = last;
        if (ch == 0 && lane < UU) top[bh * UU + lane] = qpos_s[lane];  // persist for comb
    } else {
        // ---- waves 1-3: stage V^T chunk (2048 tasks over 192 threads) ----
        int t3 = tid - 64;
#pragma unroll
        for (int i = 0; i < 11; i++) {
            int task = i * 192 + t3;
            if (task < 2048) {
                int d   = task & 63;
                int lq8 = task >> 6;
                float vv[8];
#pragma unroll
                for (int jj = 0; jj < 8; jj++)
                    vv[jj] = V[qkv_off(b, l0 + lq8 * 8 + jj, h, d)];
                short8 pk;
#pragma unroll
                for (int jj = 0; jj < 8; jj++) pk[jj] = (short)f2bf(vv[jj]);
                *reinterpret_cast<short8*>(vt + d * CHK + (((lq8 ^ (d & 31)) << 3))) = pk;
            }
        }
    }
    __syncthreads();

    f32x4 acc[3][4];
#pragma unroll
    for (int mt = 0; mt < 3; mt++)
#pragma unroll
        for (int nt = 0; nt < 4; nt++) acc[mt][nt] = (f32x4){0.f, 0.f, 0.f, 0.f};

#pragma unroll
    for (int ks = 0; ks < 2; ks++) {
        int k0 = ks * 32 + g * 8;
        short8 af[3];
#pragma unroll
        for (int mt = 0; mt < 3; mt++) {
            int row = mt * 16 + c;
            af[mt] = ld_bf8_g(Q + qkv_off(b, qpos_s[row], h, k0));
        }
#pragma unroll
        for (int nt = 0; nt < 4; nt++) {
            int kl = l0 + w * 64 + nt * 16 + c;
            short8 bf = ld_bf8_g(K + qkv_off(b, kl, h, k0));
#pragma unroll
            for (int mt = 0; mt < 3; mt++)
                acc[mt][nt] = __builtin_amdgcn_mfma_f32_16x16x32_bf16(af[mt], bf, acc[mt][nt], 0, 0, 0);
        }
    }

    float tmax[3][4];
#pragma unroll
    for (int mt = 0; mt < 3; mt++)
#pragma unroll
        for (int r = 0; r < 4; r++) {
            float m = fmaxf(fmaxf(acc[mt][0][r], acc[mt][1][r]),
                            fmaxf(acc[mt][2][r], acc[mt][3][r]));
            m = fmaxf(m, __shfl_xor(m, 1));
            m = fmaxf(m, __shfl_xor(m, 2));
            m = fmaxf(m, __shfl_xor(m, 4));
            m = fmaxf(m, __shfl_xor(m, 8));
            tmax[mt][r] = m;
        }
    if (c == 0) {
#pragma unroll
        for (int mt = 0; mt < 3; mt++)
#pragma unroll
            for (int r = 0; r < 4; r++)
                red_m[w][mt * 16 + g * 4 + r] = tmax[mt][r];
    }
    __syncthreads();

    float tse[3][4];
#pragma unroll
    for (int mt = 0; mt < 3; mt++)
#pragma unroll
        for (int r = 0; r < 4; r++) {
            int row = mt * 16 + g * 4 + r;
            float m = fmaxf(fmaxf(red_m[0][row], red_m[1][row]),
                            fmaxf(red_m[2][row], red_m[3][row]));
            float s = 0.f;
#pragma unroll
            for (int nt = 0; nt < 4; nt++) {
                float p = __expf(scale * (acc[mt][nt][r] - m));
                acc[mt][nt][r] = p;
                s += p;
                p_lds[row * CHK + w * 64 + nt * 16 + c] = f2bf(p);
            }
            s += __shfl_xor(s, 1);
            s += __shfl_xor(s, 2);
            s += __shfl_xor(s, 4);
            s += __shfl_xor(s, 8);
            tse[mt][r] = s;
        }
    if (c == 0) {
#pragma unroll
        for (int mt = 0; mt < 3; mt++)
#pragma unroll
            for (int r = 0; r < 4; r++)
                red_se[w][mt * 16 + g * 4 + r] = tse[mt][r];
    }
    __syncthreads();

    if (tid < RPAD) {
        float mm = fmaxf(fmaxf(red_m[0][tid], red_m[1][tid]),
                         fmaxf(red_m[2][tid], red_m[3][tid]));
        float ss = red_se[0][tid] + red_se[1][tid] + red_se[2][tid] + red_se[3][tid];
        m_ws[blk * RPAD + tid]  = mm;
        se_ws[blk * RPAD + tid] = ss;
    }

    f32x4 acc2[3];
#pragma unroll
    for (int mt = 0; mt < 3; mt++) acc2[mt] = (f32x4){0.f, 0.f, 0.f, 0.f};

#pragma unroll
    for (int ks = 0; ks < 8; ks++) {
        int slot = ks * 4 + g;
        int d    = w * 16 + c;
        short8 bf = *reinterpret_cast<const short8*>(
            vt + d * CHK + ((slot ^ (d & 31)) << 3));
#pragma unroll
        for (int mt = 0; mt < 3; mt++) {
            short8 af = *reinterpret_cast<const short8*>(
                p_lds + (mt * 16 + c) * CHK + ks * 32 + g * 8);
            acc2[mt] = __builtin_amdgcn_mfma_f32_16x16x32_bf16(af, bf, acc2[mt], 0, 0, 0);
        }
    }

#pragma unroll
    for (int mt = 0; mt < 3; mt++)
#pragma unroll
        for (int r = 0; r < 4; r++) {
            int row = mt * 16 + g * 4 + r;
            pv_ws[((size_t)blk * RPAD + row) * 64 + w * 16 + c] = acc2[mt][r];
        }
}

// ---------------- K3: combine chunk partials, write selected rows ----------------
__global__ __launch_bounds__(256) void kernel_attn_comb(const int* __restrict__ top,
                                                        const float* __restrict__ m_ws,
                                                        const float* __restrict__ se_ws,
                                                        const float* __restrict__ pv_ws,
                                                        float* __restrict__ out) {
    int bh = blockIdx.x;
    int b = bh >> 3, h = bh & 7;
    const float scale = 0.125f;
    for (int idx = threadIdx.x; idx < UU * 64; idx += 256) {
        int r = idx >> 6, d = idx & 63;
        float mc[NCHK];
        float mm = -INFINITY;
#pragma unroll
        for (int ch = 0; ch < NCHK; ch++) {
            mc[ch] = m_ws[(bh * NCHK + ch) * RPAD + r];
            mm = fmaxf(mm, mc[ch]);
        }
        float num = 0.f, den = 0.f;
#pragma unroll
        for (int ch = 0; ch < NCHK; ch++) {
            float f = __expf(scale * (mc[ch] - mm));
            num += f * pv_ws[((size_t)(bh * NCHK + ch) * RPAD + r) * 64 + d];
            den += f * se_ws[(bh * NCHK + ch) * RPAD + r];
        }
        out[qkv_off(b, top[bh * UU + r], h, d)] = num / den;
    }
}

extern "C" void kernel_launch(void* const* d_in, const int* in_sizes, int n_in,
                              void* d_out, int out_size, void* d_ws, size_t ws_size,
                              hipStream_t stream) {
    const float* Q    = (const float*)d_in[0];
    const float* K    = (const float*)d_in[1];
    const float* V    = (const float*)d_in[2];
    const int*   sidx = (const int*)d_in[3];
    float* out = (float*)d_out;

    char* ws = (char*)d_ws;
    float* M     = (float*)(ws);                // 256 KiB
    int*   top   = (int*)  (ws + 262144);       // 9 KiB
    float* m_ws  = (float*)(ws + 272384);       // 48 KiB
    float* se_ws = (float*)(ws + 321536);       // 48 KiB
    float* pv_ws = (float*)(ws + 370688);       // 3 MiB

    kernel_M_cumsum <<<CSBLOCKS + MBLOCKS, 512, 0, stream>>>(Q, K, V, sidx, M, out);
    kernel_attn_part<<<BH * NCHK, 256, 0, stream>>>(Q, K, V, M, top, m_ws, se_ws, pv_ws);
    kernel_attn_comb<<<BH, 256, 0, stream>>>(top, m_ws, se_ws, pv_ws, out);
}